// Round 8
// baseline (314.794 us; speedup 1.0000x reference)
//
#include <hip/hip_runtime.h>

typedef __bf16 bf16;
typedef __attribute__((ext_vector_type(8))) __bf16 bf16x8;
typedef __attribute__((ext_vector_type(4))) __bf16 bf16x4;
typedef __attribute__((ext_vector_type(4))) float f32x4;

#define S_LEN 2048
#define DM 1024
#define NB 4

// ---- async 16B global -> LDS (global_load_lds_dwordx4) ----
__device__ __forceinline__ void async_copy16(const void* g, void* l)
{
    __builtin_amdgcn_global_load_lds(
        (const __attribute__((address_space(1))) unsigned int*)g,
        (__attribute__((address_space(3))) unsigned int*)l,
        16, 0, 0);
}

#define VM_WAIT8 asm volatile("s_waitcnt vmcnt(8)" ::: "memory")
#define VM_WAIT0 asm volatile("s_waitcnt vmcnt(0)" ::: "memory")
#define LGKM0    asm volatile("s_waitcnt lgkmcnt(0)" ::: "memory")
#define BAR      asm volatile("s_barrier" ::: "memory")

// =====================================================================
// Shared fragment-read + MFMA for the 128x128 NT tile (both cores).
// LDS layout: A tile 16 KB (128 rows x 128 B), B tile 16 KB; chunk c of
// row r holds source chunk (c ^ (r&7)) -- XOR swizzle, conflict-free.
// =====================================================================

__device__ __forceinline__ void read_frags(const char* bufA, const char* bufB,
                                           int wr, int wc, int l16, int quad,
                                           bf16x8 (&af)[2][4], bf16x8 (&bfr)[2][4])
{
    const int swz = l16 & 7;
#pragma unroll
    for (int kk = 0; kk < 2; kk++) {
        const int col = (((kk << 2) + quad) ^ swz) << 4;
#pragma unroll
        for (int t = 0; t < 4; t++) {
            af[kk][t]  = *(const bf16x8*)(bufA + (wr * 64 + t * 16 + l16) * 128 + col);
            bfr[kk][t] = *(const bf16x8*)(bufB + (wc * 64 + t * 16 + l16) * 128 + col);
        }
    }
}

__device__ __forceinline__ void mfma_all(const bf16x8 (&af)[2][4],
                                         const bf16x8 (&bfr)[2][4],
                                         f32x4 (&acc)[4][4])
{
#pragma unroll
    for (int kk = 0; kk < 2; kk++)
#pragma unroll
        for (int rt = 0; rt < 4; rt++)
#pragma unroll
            for (int ct = 0; ct < 4; ct++)
                acc[rt][ct] = __builtin_amdgcn_mfma_f32_16x16x32_bf16(
                    af[kk][rt], bfr[kk][ct], acc[rt][ct], 0, 0, 0);
}

// =====================================================================
// bf16-source core (PROVEN, unchanged): global_load_lds DMA staging.
// Used by qk (Qb,Kb) and pv (P,Vt). kSteps even >= 2.
// =====================================================================

__device__ __forceinline__ void stage_issue(const char* aGk, size_t aRow32,
                                            const char* bGk, size_t bRow32,
                                            char* aL, char* bL)
{
#pragma unroll
    for (int i = 0; i < 4; i++) {
        async_copy16(aGk + i * aRow32, aL + i * 4096);
        async_copy16(bGk + i * bRow32, bL + i * 4096);
    }
}

__device__ __forceinline__ void gemm_tile(
    const bf16* __restrict__ A, int lda,
    const bf16* __restrict__ B, int ldb,
    int kSteps, char* smem, f32x4 (&acc)[4][4])
{
    const int tid = threadIdx.x;
    const int w = tid >> 6, lane = tid & 63;
    const int quad = lane >> 4, l16 = lane & 15;
    const int wr = w >> 1, wc = w & 1;

#pragma unroll
    for (int i = 0; i < 4; i++)
#pragma unroll
        for (int j = 0; j < 4; j++) acc[i][j] = f32x4{0.f, 0.f, 0.f, 0.f};

    const int srow = tid >> 3;
    const int sc8  = tid & 7;
    const int srcCol = (sc8 ^ (srow & 7)) * 16;
    const char* aG = (const char*)(A + (size_t)srow * lda) + srcCol;
    const char* bG = (const char*)(B + (size_t)srow * ldb) + srcCol;
    const size_t aRow32 = (size_t)lda * 64;
    const size_t bRow32 = (size_t)ldb * 64;
    char* aL0 = smem +     0 + w * 1024;
    char* bL0 = smem + 16384 + w * 1024;
    char* aL1 = smem + 32768 + w * 1024;
    char* bL1 = smem + 49152 + w * 1024;

    stage_issue(aG,       aRow32, bG,       bRow32, aL0, bL0);   // tile 0 -> buf0
    stage_issue(aG + 128, aRow32, bG + 128, bRow32, aL1, bL1);   // tile 1 -> buf1

    for (int ks = 0; ks < kSteps; ks += 2) {
        const bool more = (ks + 2 < kSteps);
        bf16x8 af[2][4], bfr[2][4];

        VM_WAIT8;
        BAR;
        read_frags(smem, smem + 16384, wr, wc, l16, quad, af, bfr);
        LGKM0;
        BAR;
        if (more)
            stage_issue(aG + (size_t)(ks + 2) * 128, aRow32,
                        bG + (size_t)(ks + 2) * 128, bRow32, aL0, bL0);
        mfma_all(af, bfr, acc);

        if (more) { VM_WAIT8; } else { VM_WAIT0; }
        BAR;
        read_frags(smem + 32768, smem + 49152, wr, wc, l16, quad, af, bfr);
        LGKM0;
        BAR;
        if (more)
            stage_issue(aG + (size_t)(ks + 3) * 128, aRow32,
                        bG + (size_t)(ks + 3) * 128, bRow32, aL1, bL1);
        mfma_all(af, bfr, acc);
    }
}

// =====================================================================
// ROUND-8: fp32-source core. Stages global fp32 -> regs -> cvt bf16 ->
// ds_write (swizzle applied on the SOURCE chunk index; LDS dest linear,
// byte-identical layout to the DMA core -> read_frags unchanged).
// Eliminates the prep conversion pass entirely.
// Publication safety = same 2-barrier rhythm: a wave's ds_writes (tile
// t+2, issued at phase t) are drained by its own LGKM0 at phase t+1
// (lgkmcnt covers DS writes+reads) and published by phase t+2's first
// BAR, exactly when that buffer is next read. In-flight fp32 loads are
// consumed via vmcnt(0) one phase (~650ns) after issue (> HBM latency).
// Staging regs: 16 x f32x4 = 64 VGPR, live ~1 phase; LDS (64 KB) caps
// occupancy at 2 blocks/CU, so VGPR up to 256 is free.
// =====================================================================

__device__ __forceinline__ void loads_f32(const float* aG, int lda,
                                          const float* bG, int ldb, int t,
                                          f32x4 (&sA)[4][2], f32x4 (&sB)[4][2])
{
#pragma unroll
    for (int i = 0; i < 4; i++) {
        const float* ap = aG + (size_t)i * 32 * lda + t * 64;
        const float* bp = bG + (size_t)i * 32 * ldb + t * 64;
        sA[i][0] = *(const f32x4*)(ap);
        sA[i][1] = *(const f32x4*)(ap + 4);
        sB[i][0] = *(const f32x4*)(bp);
        sB[i][1] = *(const f32x4*)(bp + 4);
    }
}

__device__ __forceinline__ void cvtwrite(char* aL, char* bL,
                                         const f32x4 (&sA)[4][2], const f32x4 (&sB)[4][2])
{
#pragma unroll
    for (int i = 0; i < 4; i++) {
        bf16x8 oa, ob;
#pragma unroll
        for (int e = 0; e < 4; e++) {
            oa[e] = (bf16)sA[i][0][e]; oa[e + 4] = (bf16)sA[i][1][e];
            ob[e] = (bf16)sB[i][0][e]; ob[e + 4] = (bf16)sB[i][1][e];
        }
        *(bf16x8*)(aL + i * 4096) = oa;
        *(bf16x8*)(bL + i * 4096) = ob;
    }
}

// A: 128 rows x K fp32 (lda elems); B: 128 rows x K fp32 (ldb). kSteps>=2.
__device__ __forceinline__ void gemm_tile_f32(
    const float* __restrict__ A, int lda,
    const float* __restrict__ B, int ldb,
    int kSteps, char* smem, f32x4 (&acc)[4][4])
{
    const int tid = threadIdx.x;
    const int w = tid >> 6, lane = tid & 63;
    const int quad = lane >> 4, l16 = lane & 15;
    const int wr = w >> 1, wc = w & 1;

#pragma unroll
    for (int i = 0; i < 4; i++)
#pragma unroll
        for (int j = 0; j < 4; j++) acc[i][j] = f32x4{0.f, 0.f, 0.f, 0.f};

    const int srow = tid >> 3;                 // 0..31 (rows +i*32)
    const int sc8  = tid & 7;                  // dest chunk (linear)
    const int srcChunk = sc8 ^ (srow & 7);     // swizzled source chunk
    const float* aG = A + (size_t)srow * lda + srcChunk * 8;
    const float* bG = B + (size_t)srow * ldb + srcChunk * 8;
    char* aL = smem + tid * 16;                // == w*1024 + lane*16 (DMA-identical)
    char* bL = smem + 16384 + tid * 16;

    f32x4 sA[4][2], sB[4][2];
    loads_f32(aG, lda, bG, ldb, 0, sA, sB);
    VM_WAIT0;
    cvtwrite(aL, bL, sA, sB);                  // buf0 <- tile 0
    loads_f32(aG, lda, bG, ldb, 1, sA, sB);
    VM_WAIT0;
    cvtwrite(aL + 32768, bL + 32768, sA, sB);  // buf1 <- tile 1
    if (kSteps > 2) loads_f32(aG, lda, bG, ldb, 2, sA, sB);
    LGKM0;                                     // own ds_writes drained

    for (int t = 0; t < kSteps; t++) {
        const int boff = (t & 1) * 32768;
        bf16x8 af[2][4], bfr[2][4];
        BAR;                                   // publish buf[t&1] (writers drained)
        read_frags(smem + boff, smem + boff + 16384, wr, wc, l16, quad, af, bfr);
        LGKM0;                                 // frags in regs + my old writes drained
        BAR;                                   // all waves done reading -> overwritable
        if (t + 2 < kSteps) {
            VM_WAIT0;                          // loads(t+2) landed (issued 1 phase ago)
            cvtwrite(aL + boff, bL + boff, sA, sB);
            if (t + 3 < kSteps)
                loads_f32(aG, lda, bG, ldb, t + 3, sA, sB);
        }
        mfma_all(af, bfr, acc);
    }
    // nothing outstanding: last loads consumed at t = kSteps-3.
}

// ---- projection Q,K from RAW fp32 inputs (no prep). Grid 1032: bids
// 0..7 zero lsum (retire instantly, done long before qk launches);
// 8..1031 = 1024 GEMM blocks (exactly 2 rounds at 2 blocks/CU). ----
__global__ __launch_bounds__(256, 2) void projqk_kernel(
    const float* __restrict__ Eq, const float* __restrict__ Ek,
    const float* __restrict__ Wq, const float* __restrict__ Wk,
    const float* __restrict__ bq, const float* __restrict__ bk,
    bf16* __restrict__ Qo, bf16* __restrict__ Ko, float* __restrict__ lsum)
{
    __shared__ __align__(16) char smem[65536];
    const int bid = blockIdx.x;
    const int tid = threadIdx.x;

    if (bid < 8) {   // lsum zero: 8 blocks x 1024 floats
        *(f32x4*)(lsum + (bid * 1024) + tid * 4) = f32x4{0.f, 0.f, 0.f, 0.f};
        return;
    }
    const int g = bid - 8;
    const int c = g & 7;
    const int j = g >> 3;            // 0..127
    const int z = j >> 6;            // 0..1
    const int r64 = j & 63;
    const int m0 = (c * 8 + (r64 >> 3)) * 128;
    const int n0 = (r64 & 7) * 128;

    const float* E    = z == 0 ? Eq : Ek;
    const float* W    = z == 0 ? Wq : Wk;
    const float* bias = z == 0 ? bq : bk;

    f32x4 acc[4][4];
    gemm_tile_f32(E + (size_t)m0 * DM, DM, W + (size_t)n0 * DM, DM, DM / 64, smem, acc);

    const int w = tid >> 6, lane = tid & 63;
    const int quad = lane >> 4, l16 = lane & 15;
    const int wr = w >> 1, wc = w & 1;
    const int nBase = n0 + wc * 64;

    float bcol[4];
#pragma unroll
    for (int ct = 0; ct < 4; ct++) bcol[ct] = bias[nBase + ct * 16 + l16];

    __syncthreads();   // smem reuse (no loads outstanding; ds drained in-loop)
    bf16* Tt = (bf16*)smem;   // 128 x 136 (rows 16B-aligned)
#pragma unroll
    for (int rt = 0; rt < 4; rt++)
#pragma unroll
        for (int ct = 0; ct < 4; ct++)
#pragma unroll
            for (int r = 0; r < 4; r++)
                Tt[(wr * 64 + rt * 16 + quad * 4 + r) * 136 + wc * 64 + ct * 16 + l16]
                    = (bf16)(acc[rt][ct][r] + bcol[ct]);
    __syncthreads();
    bf16* O = z == 0 ? Qo : Ko;
    const int row = tid >> 1, half = tid & 1;
    const bf16* src = Tt + row * 136 + half * 64;
    bf16* dst = O + (size_t)(m0 + row) * DM + n0 + half * 64;
#pragma unroll
    for (int i = 0; i < 8; i++)
        *(bf16x8*)(dst + i * 8) = *(const bf16x8*)(src + i * 8);
}

// ---- MERGED: qk (bids 0..1023, bf16 core on Qb,Kb) + projV (bids
// 1024..1535, fp32 core on RAW Ev,Wv). qk's dead causal blocks retire in
// the first wave; uniform projV tiles backfill. ----
__global__ __launch_bounds__(256, 2) void projv_qk_kernel(
    const float* __restrict__ Ev, const float* __restrict__ Wv,
    const float* __restrict__ bv, bf16* __restrict__ Vt,
    const bf16* __restrict__ Q, const bf16* __restrict__ K,
    const int* __restrict__ maskp, bf16* __restrict__ P, float* __restrict__ lsum)
{
    __shared__ __align__(16) char smem[65536];
    const int bid = blockIdx.x;
    const int tid = threadIdx.x;
    const int w = tid >> 6, lane = tid & 63;
    const int quad = lane >> 4, l16 = lane & 15;
    const int wr = w >> 1, wc = w & 1;

    if (bid < 1024) {
        // ================= qk: P = exp(Q K^T / 32), row sums =============
        const int c = bid & 7;
        const int j = bid >> 3;              // 0..127
        const int b = j >> 5;
        const int jj = j & 31;
        const int kt = (jj < 16) ? c : (15 - c);
        const int qt = jj & 15;
        const bool causal = (maskp[0] != 0);
        if (causal && kt > qt) return;

        f32x4 acc[4][4];
        const bf16* Qb = Q + ((size_t)(b * S_LEN + qt * 128)) * DM;
        const bf16* Kb = K + ((size_t)(b * S_LEN + kt * 128)) * DM;
        gemm_tile(Qb, DM, Kb, DM, DM / 64, smem, acc);

        const float scale = 0.03125f;  // 1/sqrt(1024)

        __syncthreads();
        bf16* Pt = (bf16*)smem;   // 128 x 136
#pragma unroll
        for (int rt = 0; rt < 4; rt++)
#pragma unroll
            for (int r = 0; r < 4; r++) {
                const int rloc = wr * 64 + rt * 16 + quad * 4 + r;
                const int qg = qt * 128 + rloc;
#pragma unroll
                for (int ct = 0; ct < 4; ct++) {
                    const int kg = kt * 128 + wc * 64 + ct * 16 + l16;
                    float p = (!causal || kg <= qg) ? __expf(acc[rt][ct][r] * scale) : 0.0f;
                    Pt[rloc * 136 + wc * 64 + ct * 16 + l16] = (bf16)p;
                }
            }
        __syncthreads();

        bf16* Pb = P + (size_t)b * S_LEN * S_LEN;
        float* lb = lsum + b * S_LEN;
        const int row = tid >> 1, half = tid & 1;
        const bf16* src = Pt + row * 136 + half * 64;
        bf16* dst = Pb + (size_t)(qt * 128 + row) * S_LEN + kt * 128 + half * 64;
        float rs = 0.0f;
#pragma unroll
        for (int i = 0; i < 8; i++) {
            bf16x8 x = *(const bf16x8*)(src + i * 8);
            *(bf16x8*)(dst + i * 8) = x;
#pragma unroll
            for (int e = 0; e < 8; e++) rs += (float)x[e];   // sum rounded values PV uses
        }
        rs += __shfl_xor(rs, 1);
        if (half == 0) atomicAdd(&lb[qt * 128 + row], rs);
    } else {
        // ================= projV (fp32 core): Vt[b][d][s] ===============
        const int vbid = bid - 1024;     // 0..511
        const int c = vbid & 7;
        const int r64 = vbid >> 3;       // 0..63
        const int m0 = (c * 8 + (r64 >> 3)) * 128;
        const int n0 = (r64 & 7) * 128;

        f32x4 acc[4][4];
        gemm_tile_f32(Ev + (size_t)m0 * DM, DM, Wv + (size_t)n0 * DM, DM, DM / 64, smem, acc);

        const int nBase = n0 + wc * 64;
        float bcol[4];
#pragma unroll
        for (int ct = 0; ct < 4; ct++) bcol[ct] = bv[nBase + ct * 16 + l16];

        // Vt[b][d][s]: lane holds 4 consecutive s for fixed d -> 8B store
        const int mBase = m0 + wr * 64;
#pragma unroll
        for (int rt = 0; rt < 4; rt++) {
            const int m = mBase + rt * 16 + quad * 4;
            const int bb = m >> 11;
            const int s  = m & 2047;
#pragma unroll
            for (int ct = 0; ct < 4; ct++) {
                const int n = nBase + ct * 16 + l16;
                bf16x4 o;
                o[0] = (bf16)(acc[rt][ct][0] + bcol[ct]);
                o[1] = (bf16)(acc[rt][ct][1] + bcol[ct]);
                o[2] = (bf16)(acc[rt][ct][2] + bcol[ct]);
                o[3] = (bf16)(acc[rt][ct][3] + bcol[ct]);
                *(bf16x4*)(Vt + ((size_t)(bb * DM + n)) * S_LEN + s) = o;
            }
        }
    }
}

// ---- O = (P @ Vt^T) / l. 512 blocks (2/CU). ROUND-5 TABLE (best pv):
// stride-32 CU pairing (confirmed round-4); kk and kk+4 sum to 15 ->
// every CU-pair totals 34 K-steps. par0 0x74308BCF; par1 0x65219ADE.
// XCD c owns (b=c>>1, par=c&1): P-panels + Vt[b] L2-local. ----
__global__ __launch_bounds__(256) void pv_kernel(
    const bf16* __restrict__ P, const bf16* __restrict__ Vt,
    const float* __restrict__ lsum, const int* __restrict__ maskp,
    float* __restrict__ Out)
{
    const int bid = blockIdx.x;          // 0..511
    const int c = bid & 7;               // XCD
    const int b = c >> 1;
    const int par = c & 1;
    const int idx = bid >> 3;            // 0..63
    const int dt = idx & 7;
    const int qi = idx >> 3;             // 0..7
    const int kk = (qi + dt) & 7;
    const unsigned tbl = par ? 0x65219ADEu : 0x74308BCFu;
    const int qt = (tbl >> (kk * 4)) & 15;
    const bool causal = (maskp[0] != 0);
    const int kSteps = causal ? (qt + 1) * 2 : (S_LEN / 64);

    __shared__ __align__(16) char smem[65536];

    f32x4 acc[4][4];
    const bf16* Pb = P + ((size_t)b * S_LEN + qt * 128) * S_LEN;
    const bf16* Vb = Vt + ((size_t)(b * DM + dt * 128)) * S_LEN;
    gemm_tile(Pb, S_LEN, Vb, S_LEN, kSteps, smem, acc);

    const int tid = threadIdx.x;
    const int w = tid >> 6, lane = tid & 63;
    const int quad = lane >> 4, l16 = lane & 15;
    const int wr = w >> 1, wc = w & 1;

    const float* lb = lsum + b * S_LEN;
    float inv[4][4];
#pragma unroll
    for (int rt = 0; rt < 4; rt++)
#pragma unroll
        for (int r = 0; r < 4; r++)
            inv[rt][r] = 1.0f / lb[qt * 128 + wr * 64 + rt * 16 + quad * 4 + r];

    __syncthreads();
    float* Ot = (float*)smem;   // 64 x 132 (rows 16B-aligned)
#pragma unroll
    for (int h = 0; h < 2; h++) {
        if (wr == h) {
#pragma unroll
            for (int rt = 0; rt < 4; rt++)
#pragma unroll
                for (int r = 0; r < 4; r++) {
                    const int rloc = rt * 16 + quad * 4 + r;
#pragma unroll
                    for (int ct = 0; ct < 4; ct++)
                        Ot[rloc * 132 + wc * 64 + ct * 16 + l16] = acc[rt][ct][r] * inv[rt][r];
                }
        }
        __syncthreads();
        const int row = tid >> 2, qq = tid & 3;
        const float* src = Ot + row * 132 + qq * 32;
        float* dst = Out + (size_t)(b * S_LEN + qt * 128 + h * 64 + row) * DM + dt * 128 + qq * 32;
#pragma unroll
        for (int i = 0; i < 8; i++)
            *(f32x4*)(dst + i * 4) = *(const f32x4*)(src + i * 4);
        __syncthreads();
    }
}

extern "C" void kernel_launch(void* const* d_in, const int* in_sizes, int n_in,
                              void* d_out, int out_size, void* d_ws, size_t ws_size,
                              hipStream_t stream)
{
    const float* Eq = (const float*)d_in[0];
    const float* Ek = (const float*)d_in[1];
    const float* Ev = (const float*)d_in[2];
    const float* Wq = (const float*)d_in[3];
    const float* bq = (const float*)d_in[4];
    const float* Wk = (const float*)d_in[5];
    const float* bk = (const float*)d_in[6];
    const float* Wv = (const float*)d_in[7];
    const float* bv = (const float*)d_in[8];
    const int* maskp = (const int*)d_in[9];
    float* Out = (float*)d_out;

    // ws layout (~81 MB): [Qb 16M][Kb 16M][Vtb 16M][lsum 32K][P 32M]
    char* ws = (char*)d_ws;
    const size_t SZ_QKV = (size_t)NB * S_LEN * DM * 2;
    bf16* Qb  = (bf16*)(ws);
    bf16* Kb  = (bf16*)(ws + SZ_QKV);
    bf16* Vtb = (bf16*)(ws + 2 * SZ_QKV);
    float* lsum = (float*)(ws + 3 * SZ_QKV);
    bf16* Pbuf = (bf16*)(ws + 3 * SZ_QKV + (1 << 20));

    projqk_kernel<<<1032, 256, 0, stream>>>(
        Eq, Ek, Wq, Wk, bq, bk, Qb, Kb, lsum);

    projv_qk_kernel<<<1536, 256, 0, stream>>>(
        Ev, Wv, bv, Vtb, Qb, Kb, maskp, Pbuf, lsum);

    pv_kernel<<<512, 256, 0, stream>>>(Pbuf, Vtb, lsum, maskp, Out);
}